// Round 4
// baseline (892.800 us; speedup 1.0000x reference)
//
#include <hip/hip_runtime.h>

#define NSEQ 256
#define NRES 1024
#define CM   256
#define CC   32
#define CZ   128
#define EPS  1e-5f
#define SROW (NRES * CM)   // stride between s-rows of x for fixed r
#define MCH  32            // m-chunk size (floats)
#define XPAD 36            // padded row stride for x chunk (floats)

typedef float f4v __attribute__((ext_vector_type(4)));

// ============ Kernel A: compute pre_pair[r][z] -> d_ws (512 KB) ============
// One block per residue r. 256 threads (4 waves), 2 blocks/CU (LDS-limited).
__launch_bounds__(256, 2)
__global__ void opm_stage1(const float* __restrict__ msa,
                           const float* __restrict__ nw,
                           const float* __restrict__ nb,
                           const float* __restrict__ w_ab,
                           const float* __restrict__ b_ab,
                           const float* __restrict__ w_out,
                           const float* __restrict__ b_out,
                           float* __restrict__ pre)     // (NRES, CZ)
{
    __shared__ float wt[CM * CC];        // 32 KB  [m][c]
    __shared__ float xt[NSEQ * XPAD];    // 36 KB  x chunk [s][m']; later a[s][c] stride 32
    __shared__ float o_lds[CC * CC];     // 4 KB
    __shared__ float K1p[8 * CC], K2p[8 * CC];
    __shared__ float K1[CC], K2[CC];
    __shared__ float pre_part[2 * CZ];
    __shared__ float pre_lds[CZ];

    const int tid = threadIdx.x;
    const int r   = blockIdx.x;

    // ---------------- P0: stage w' transposed ----------------
    {
        const int c  = tid & 31;
        const int m0 = tid >> 5;
        #pragma unroll
        for (int k = 0; k < 32; ++k) {
            const int m = m0 + (k << 3);
            wt[m * CC + c] = nw[m] * w_ab[c * CM + m];
        }
    }
    __syncthreads();
    {
        const int c    = tid & 31;
        const int part = tid >> 5;
        float k1 = 0.f, k2 = 0.f;
        #pragma unroll 8
        for (int i = 0; i < 32; ++i) {
            const int m = part * 32 + i;
            k1 += wt[m * CC + c];
            k2 = fmaf(nb[m], w_ab[c * CM + m], k2);
        }
        K1p[part * CC + c] = k1;
        K2p[part * CC + c] = k2;
    }
    __syncthreads();
    if (tid < CC) {
        float k1 = 0.f, k2 = 0.f;
        #pragma unroll
        for (int p = 0; p < 8; ++p) { k1 += K1p[p * CC + tid]; k2 += K2p[p * CC + tid]; }
        K1[tid] = k1;
        K2[tid] = k2 + b_ab[tid];
    }

    // ---------------- P1: G-phase, m-chunked with register prefetch ----------------
    const int sc = tid & 7;
    const int sg = tid >> 3;
    const int c0 = sc * 4;
    const float* xr = msa + (size_t)r * CM;

    float G[8][4];
    float ssum[8], ssq[8];
    #pragma unroll
    for (int j = 0; j < 8; ++j) {
        ssum[j] = 0.f; ssq[j] = 0.f;
        #pragma unroll
        for (int cc = 0; cc < 4; ++cc) G[j][cc] = 0.f;
    }

    float4 pf[8];
    #pragma unroll
    for (int k = 0; k < 8; ++k)
        pf[k] = *(const float4*)(xr + (size_t)(sg + (k << 5)) * SROW + (sc << 2));

    for (int mb = 0; mb < CM; mb += MCH) {
        __syncthreads();
        #pragma unroll
        for (int k = 0; k < 8; ++k)
            *(float4*)&xt[(sg + (k << 5)) * XPAD + (sc << 2)] = pf[k];
        __syncthreads();
        if (mb + MCH < CM) {
            #pragma unroll
            for (int k = 0; k < 8; ++k)
                pf[k] = *(const float4*)(xr + (size_t)(sg + (k << 5)) * SROW + (mb + MCH) + (sc << 2));
        }
        #pragma unroll
        for (int mm = 0; mm < MCH; mm += 4) {
            const float4 w0 = *(const float4*)&wt[(mb + mm + 0) * CC + c0];
            const float4 w1 = *(const float4*)&wt[(mb + mm + 1) * CC + c0];
            const float4 w2 = *(const float4*)&wt[(mb + mm + 2) * CC + c0];
            const float4 w3 = *(const float4*)&wt[(mb + mm + 3) * CC + c0];
            #pragma unroll
            for (int j = 0; j < 8; ++j) {
                const float4 x4 = *(const float4*)&xt[(sg + (j << 5)) * XPAD + mm];
                G[j][0] = fmaf(x4.x, w0.x, fmaf(x4.y, w1.x, fmaf(x4.z, w2.x, fmaf(x4.w, w3.x, G[j][0]))));
                G[j][1] = fmaf(x4.x, w0.y, fmaf(x4.y, w1.y, fmaf(x4.z, w2.y, fmaf(x4.w, w3.y, G[j][1]))));
                G[j][2] = fmaf(x4.x, w0.z, fmaf(x4.y, w1.z, fmaf(x4.z, w2.z, fmaf(x4.w, w3.z, G[j][2]))));
                G[j][3] = fmaf(x4.x, w0.w, fmaf(x4.y, w1.w, fmaf(x4.z, w2.w, fmaf(x4.w, w3.w, G[j][3]))));
                ssum[j] += (x4.x + x4.y) + (x4.z + x4.w);
                ssq[j]  = fmaf(x4.x, x4.x, fmaf(x4.y, x4.y, fmaf(x4.z, x4.z, fmaf(x4.w, x4.w, ssq[j]))));
            }
        }
    }

    // ---------------- P2: finalize a, store into xt (stride 32) ----------------
    float a_reg[8][4];
    {
        const float k1a = K1[c0 + 0], k1b = K1[c0 + 1], k1c = K1[c0 + 2], k1d = K1[c0 + 3];
        const float k2a = K2[c0 + 0], k2b = K2[c0 + 1], k2c = K2[c0 + 2], k2d = K2[c0 + 3];
        #pragma unroll
        for (int j = 0; j < 8; ++j) {
            const float mu   = ssum[j] * (1.f / CM);
            const float var  = ssq[j] * (1.f / CM) - mu * mu;
            const float rstd = 1.f / sqrtf(var + EPS);
            a_reg[j][0] = fmaf(rstd, G[j][0] - mu * k1a, k2a);
            a_reg[j][1] = fmaf(rstd, G[j][1] - mu * k1b, k2b);
            a_reg[j][2] = fmaf(rstd, G[j][2] - mu * k1c, k2c);
            a_reg[j][3] = fmaf(rstd, G[j][3] - mu * k1d, k2d);
        }
    }
    __syncthreads();
    #pragma unroll
    for (int j = 0; j < 8; ++j) {
        const int s = sg + (j << 5);
        *(float4*)&xt[s * CC + c0] =
            make_float4(a_reg[j][0], a_reg[j][1], a_reg[j][2], a_reg[j][3]);
    }
    __syncthreads();

    // ---------------- P3: o = A^T A / NSEQ, 2x2 tile per thread ----------------
    const int xi = (tid >> 4) << 1;
    const int yi = (tid & 15) << 1;
    float o00 = 0.f, o01 = 0.f, o10 = 0.f, o11 = 0.f;
    #pragma unroll 4
    for (int s = 0; s < NSEQ; ++s) {
        const float2 ax = *(const float2*)&xt[s * CC + xi];
        const float2 ay = *(const float2*)&xt[s * CC + yi];
        o00 = fmaf(ax.x, ay.x, o00);
        o01 = fmaf(ax.x, ay.y, o01);
        o10 = fmaf(ax.y, ay.x, o10);
        o11 = fmaf(ax.y, ay.y, o11);
    }
    {
        const float inv_s = 1.f / NSEQ;
        *(float2*)&o_lds[xi * CC + yi]       = make_float2(o00 * inv_s, o01 * inv_s);
        *(float2*)&o_lds[(xi + 1) * CC + yi] = make_float2(o10 * inv_s, o11 * inv_s);
    }
    __syncthreads();

    // ---------------- P4: pre[z] = o . w_out[z] + b_out[z] ----------------
    {
        const int z    = tid & 127;
        const int half = tid >> 7;
        const float* wrow = w_out + (size_t)z * (CC * CC) + half * 512;
        const float* op   = o_lds + half * 512;
        float po = 0.f;
        #pragma unroll 8
        for (int k = 0; k < 512; k += 4) {
            const float4 o4 = *(const float4*)&op[k];
            const float4 w4 = *(const float4*)&wrow[k];
            po = fmaf(o4.x, w4.x, fmaf(o4.y, w4.y, fmaf(o4.z, w4.z, fmaf(o4.w, w4.w, po))));
        }
        pre_part[half * CZ + z] = po;
    }
    __syncthreads();
    if (tid < CZ) pre_lds[tid] = pre_part[tid] + pre_part[CZ + tid] + b_out[tid];
    __syncthreads();

    // ---------------- store pre row (512 B) to workspace ----------------
    if (tid < 32) {
        ((float4*)pre)[(size_t)r * 32 + tid] = *(const float4*)&pre_lds[tid * 4];
    }
}

// ============ Kernel B: broadcast pre over the s-axis ============
// 2048 blocks x 256 threads. Block b owns 16384 consecutive float4 of out
// (= half an r-slab; 32768 f4 per r). Each thread reads ONE float4 of pre
// (z4 = tid&31 is invariant across its 64 stores) and streams it out.
__launch_bounds__(256, 8)
__global__ void opm_bcast(const float* __restrict__ pre,
                          float* __restrict__ out)
{
    const int tid = threadIdx.x;
    const size_t chunk = (size_t)blockIdx.x * 16384;
    const int r = (int)(chunk >> 15);               // 32768 f4 per r-slab
    const f4v pv = ((const f4v*)pre)[(r << 5) + (tid & 31)];
    f4v* op = (f4v*)out + chunk + tid;
    #pragma unroll 8
    for (int k = 0; k < 64; ++k)
        __builtin_nontemporal_store(pv, op + (size_t)k * 256);
}

extern "C" void kernel_launch(void* const* d_in, const int* in_sizes, int n_in,
                              void* d_out, int out_size, void* d_ws, size_t ws_size,
                              hipStream_t stream) {
    const float* msa   = (const float*)d_in[0];
    const float* nw    = (const float*)d_in[1];
    const float* nb    = (const float*)d_in[2];
    const float* w_ab  = (const float*)d_in[3];
    const float* b_ab  = (const float*)d_in[4];
    const float* w_out = (const float*)d_in[5];
    const float* b_out = (const float*)d_in[6];
    float* out = (float*)d_out;
    float* pre = (float*)d_ws;   // needs NRES*CZ*4 = 512 KB of scratch

    opm_stage1<<<NRES, 256, 0, stream>>>(msa, nw, nb, w_ab, b_ab, w_out, b_out, pre);
    opm_bcast<<<2048, 256, 0, stream>>>(pre, out);
}

// Round 5
// 885.774 us; speedup vs baseline: 1.0079x; 1.0079x over previous
//
#include <hip/hip_runtime.h>

#define NSEQ 256
#define NRES 1024
#define CM   256
#define CC   32
#define CZ   128
#define EPS  1e-5f
#define MCH  16            // m-chunk (floats)
#define XTS  20            // xt row stride (16 data + 4 pad): all LDS ops <=2-way
#define ASS  34            // as row stride (32 data + 2 pad): even (float2-aligned), <=4-way

typedef float f4v __attribute__((ext_vector_type(4)));

// ============ K0: wt[m][c] = nw[m]*w_ab[c][m]; K1[c]=sum_m wt; K2[c]=sum_m nb*w_ab + b_ab ============
__launch_bounds__(256, 1)
__global__ void opm_prep(const float* __restrict__ nw, const float* __restrict__ nb,
                         const float* __restrict__ w_ab, const float* __restrict__ b_ab,
                         float* __restrict__ wt_g, float* __restrict__ k12_g)
{
    __shared__ float wt_s[CM * CC];
    const int m = threadIdx.x;          // 0..255
    const float nwm = nw[m];
    #pragma unroll 8
    for (int c = 0; c < CC; ++c)
        wt_s[m * CC + c] = nwm * w_ab[c * CM + m];
    __syncthreads();
    // write wt to global (thread m writes its row, 8 f4)
    #pragma unroll
    for (int k = 0; k < 8; ++k)
        ((f4v*)wt_g)[m * 8 + k] = *(const f4v*)&wt_s[m * CC + k * 4];
    if (m < CC) {
        float k1 = 0.f, k2 = 0.f;
        for (int mm = 0; mm < CM; ++mm) {
            k1 += wt_s[mm * CC + m];
            k2 = fmaf(nb[mm], w_ab[m * CM + mm], k2);   // w_ab row m-as-c is contiguous
        }
        k12_g[m]      = k1;
        k12_g[CC + m] = k2 + b_ab[m];
    }
}

// ============ K1: LN+linear, s-major contiguous slabs -> a[s][r][c] ============
// Block b: s = b>>2, r0 = (b&3)*256. Reads msa[s][r0..r0+256)[*] = 256KB contiguous.
// 3 blocks/CU (LDS 52.3KB), 12 waves/CU.
__launch_bounds__(256, 3)
__global__ void opm_ln_lin(const float* __restrict__ msa,
                           const float* __restrict__ wt_g,
                           const float* __restrict__ k12_g,
                           float* __restrict__ a_g)
{
    __shared__ float wt[CM * CC];        // 32 KB [m][c]
    __shared__ float xt[256 * XTS];      // 20 KB chunk: 256 rows x 16 m (+4 pad)
    __shared__ float K1c[CC], K2c[CC];

    const int tid = threadIdx.x;
    const int s   = blockIdx.x >> 2;
    const int r0  = (blockIdx.x & 3) << 8;

    // stage wt (32KB) from global: thread t handles f4 slots t+256k
    {
        const f4v* src = (const f4v*)wt_g;
        #pragma unroll
        for (int k = 0; k < 8; ++k)
            ((f4v*)wt)[tid + (k << 8)] = src[tid + (k << 8)];
        if (tid < CC) { K1c[tid] = k12_g[tid]; K2c[tid] = k12_g[CC + tid]; }
    }

    const float* xrow = msa + ((size_t)s * NRES + r0 + tid) * CM;  // thread t's row (64B/chunk)
    float4 pf[4];
    #pragma unroll
    for (int k = 0; k < 4; ++k) pf[k] = *(const float4*)(xrow + (k << 2));

    const int sc = tid & 7;              // c-quad
    const int sg = tid >> 3;             // 0..31, rows sg+32j
    const int c0 = sc << 2;

    float G[8][4];
    float ssum[8], ssq[8];
    #pragma unroll
    for (int j = 0; j < 8; ++j) {
        ssum[j] = 0.f; ssq[j] = 0.f;
        #pragma unroll
        for (int cc = 0; cc < 4; ++cc) G[j][cc] = 0.f;
    }
    __syncthreads();   // wt staged; also orders first xt write

    for (int mb = 0; mb < CM; mb += MCH) {
        #pragma unroll
        for (int k = 0; k < 4; ++k)
            *(float4*)&xt[tid * XTS + (k << 2)] = pf[k];
        __syncthreads();
        if (mb + MCH < CM) {
            #pragma unroll
            for (int k = 0; k < 4; ++k)
                pf[k] = *(const float4*)(xrow + mb + MCH + (k << 2));
        }
        #pragma unroll
        for (int mm = 0; mm < MCH; mm += 4) {
            const float4 w0 = *(const float4*)&wt[(mb + mm + 0) * CC + c0];
            const float4 w1 = *(const float4*)&wt[(mb + mm + 1) * CC + c0];
            const float4 w2 = *(const float4*)&wt[(mb + mm + 2) * CC + c0];
            const float4 w3 = *(const float4*)&wt[(mb + mm + 3) * CC + c0];
            #pragma unroll
            for (int j = 0; j < 8; ++j) {
                const float4 x4 = *(const float4*)&xt[(sg + (j << 5)) * XTS + mm];
                G[j][0] = fmaf(x4.x, w0.x, fmaf(x4.y, w1.x, fmaf(x4.z, w2.x, fmaf(x4.w, w3.x, G[j][0]))));
                G[j][1] = fmaf(x4.x, w0.y, fmaf(x4.y, w1.y, fmaf(x4.z, w2.y, fmaf(x4.w, w3.y, G[j][1]))));
                G[j][2] = fmaf(x4.x, w0.z, fmaf(x4.y, w1.z, fmaf(x4.z, w2.z, fmaf(x4.w, w3.z, G[j][2]))));
                G[j][3] = fmaf(x4.x, w0.w, fmaf(x4.y, w1.w, fmaf(x4.z, w2.w, fmaf(x4.w, w3.w, G[j][3]))));
                ssum[j] += (x4.x + x4.y) + (x4.z + x4.w);
                ssq[j]  = fmaf(x4.x, x4.x, fmaf(x4.y, x4.y, fmaf(x4.z, x4.z, fmaf(x4.w, x4.w, ssq[j]))));
            }
        }
        __syncthreads();   // readers done before next overwrite
    }

    // finalize a = rstd*(G - mu*K1) + K2, write coalesced f4
    {
        const float k1a = K1c[c0 + 0], k1b = K1c[c0 + 1], k1c = K1c[c0 + 2], k1d = K1c[c0 + 3];
        const float k2a = K2c[c0 + 0], k2b = K2c[c0 + 1], k2c = K2c[c0 + 2], k2d = K2c[c0 + 3];
        #pragma unroll
        for (int j = 0; j < 8; ++j) {
            const float mu   = ssum[j] * (1.f / CM);
            const float var  = ssq[j] * (1.f / CM) - mu * mu;
            const float rstd = 1.f / sqrtf(var + EPS);
            f4v av;
            av.x = fmaf(rstd, G[j][0] - mu * k1a, k2a);
            av.y = fmaf(rstd, G[j][1] - mu * k1b, k2b);
            av.z = fmaf(rstd, G[j][2] - mu * k1c, k2c);
            av.w = fmaf(rstd, G[j][3] - mu * k1d, k2d);
            const size_t row = (size_t)s * NRES + r0 + sg + (j << 5);
            *(f4v*)&a_g[row * CC + c0] = av;
        }
    }
}

// ============ K2: per-r Gram + projection -> pre[r][z] ============
__launch_bounds__(256, 4)
__global__ void opm_gram(const float* __restrict__ a_g,
                         const float* __restrict__ w_out,
                         const float* __restrict__ b_out,
                         float* __restrict__ pre)
{
    __shared__ float as[NSEQ * ASS];     // 34 KB  [s][c] stride 34
    __shared__ float o_lds[CC * CC];     // 4 KB
    __shared__ float pre_part[2 * CZ];
    __shared__ float pre_lds[CZ];

    const int tid = threadIdx.x;
    const int r   = blockIdx.x;

    // stage a-column: thread t = s loads its 32 floats (contiguous per lane)
    {
        const f4v* src = (const f4v*)(a_g + ((size_t)tid * NRES + r) * CC);
        #pragma unroll
        for (int k = 0; k < 8; ++k)
            *(f4v*)&as[tid * ASS + (k << 2)] = src[k];
    }
    __syncthreads();

    // Gram 2x2 per thread
    const int xi = (tid >> 4) << 1;
    const int yi = (tid & 15) << 1;
    float o00 = 0.f, o01 = 0.f, o10 = 0.f, o11 = 0.f;
    #pragma unroll 4
    for (int s = 0; s < NSEQ; ++s) {
        const float2 ax = *(const float2*)&as[s * ASS + xi];
        const float2 ay = *(const float2*)&as[s * ASS + yi];
        o00 = fmaf(ax.x, ay.x, o00);
        o01 = fmaf(ax.x, ay.y, o01);
        o10 = fmaf(ax.y, ay.x, o10);
        o11 = fmaf(ax.y, ay.y, o11);
    }
    {
        const float inv_s = 1.f / NSEQ;
        *(float2*)&o_lds[xi * CC + yi]       = make_float2(o00 * inv_s, o01 * inv_s);
        *(float2*)&o_lds[(xi + 1) * CC + yi] = make_float2(o10 * inv_s, o11 * inv_s);
    }
    __syncthreads();

    // pre[z] = o . w_out[z] + b_out[z]
    {
        const int z    = tid & 127;
        const int half = tid >> 7;
        const float* wrow = w_out + (size_t)z * (CC * CC) + half * 512;
        const float* op   = o_lds + half * 512;
        float po = 0.f;
        #pragma unroll 8
        for (int k = 0; k < 512; k += 4) {
            const float4 o4 = *(const float4*)&op[k];
            const float4 w4 = *(const float4*)&wrow[k];
            po = fmaf(o4.x, w4.x, fmaf(o4.y, w4.y, fmaf(o4.z, w4.z, fmaf(o4.w, w4.w, po))));
        }
        pre_part[half * CZ + z] = po;
    }
    __syncthreads();
    if (tid < CZ) pre_lds[tid] = pre_part[tid] + pre_part[CZ + tid] + b_out[tid];
    __syncthreads();
    if (tid < 32)
        ((f4v*)pre)[(size_t)r * 32 + tid] = *(const f4v*)&pre_lds[tid * 4];
}

// ============ K3: broadcast pre over the s-axis (plain stores) ============
__launch_bounds__(256, 8)
__global__ void opm_bcast(const float* __restrict__ pre,
                          float* __restrict__ out)
{
    const int tid = threadIdx.x;
    const size_t chunk = (size_t)blockIdx.x * 16384;   // f4 units; 2 blocks per r-slab
    const int r = blockIdx.x >> 1;
    const f4v pv = ((const f4v*)pre)[(r << 5) + (tid & 31)];
    f4v* op = (f4v*)out + chunk + tid;
    #pragma unroll 8
    for (int k = 0; k < 64; ++k)
        op[(size_t)k * 256] = pv;
}

extern "C" void kernel_launch(void* const* d_in, const int* in_sizes, int n_in,
                              void* d_out, int out_size, void* d_ws, size_t ws_size,
                              hipStream_t stream) {
    const float* msa   = (const float*)d_in[0];
    const float* nw    = (const float*)d_in[1];
    const float* nb    = (const float*)d_in[2];
    const float* w_ab  = (const float*)d_in[3];
    const float* b_ab  = (const float*)d_in[4];
    const float* w_out = (const float*)d_in[5];
    const float* b_out = (const float*)d_in[6];
    float* out = (float*)d_out;

    float* ws   = (float*)d_ws;
    float* a_g  = ws;                               // 32 MB  (NSEQ*NRES*CC)
    float* pre  = ws + (size_t)NSEQ * NRES * CC;    // 512 KB (NRES*CZ)
    float* wt_g = pre + (size_t)NRES * CZ;          // 32 KB
    float* k12  = wt_g + CM * CC;                   // 256 B

    opm_prep<<<1, 256, 0, stream>>>(nw, nb, w_ab, b_ab, wt_g, k12);
    opm_ln_lin<<<NSEQ * 4, 256, 0, stream>>>(msa, wt_g, k12, a_g);
    opm_gram<<<NRES, 256, 0, stream>>>(a_g, w_out, b_out, pre);
    opm_bcast<<<2048, 256, 0, stream>>>(pre, out);
}